// Round 10
// baseline (996.090 us; speedup 1.0000x reference)
//
#include <hip/hip_runtime.h>

#define HID 150
#define LD  160
#define NN  100000
#define NNP 100096   // padded rows: 1564 blocks * 64 rows
#define NE  800000
#define NG  128
#define NL  4
#define ODIM 6
#define BN_EPS 1e-5f
#define NSLICE 32
#define NB_SCAN 98   // ceil(NN/1024)

typedef __attribute__((ext_vector_type(8))) short short8;
typedef __attribute__((ext_vector_type(4))) float f32x4;

__device__ __forceinline__ unsigned short f2bf(float f) {
    union { float f; unsigned int u; } v; v.f = f;
    unsigned int u = v.u;
    unsigned int r = (u + 0x7FFFu + ((u >> 16) & 1u)) >> 16;
    return (unsigned short)r;
}
__device__ __forceinline__ float bf2f(unsigned short h) {
    union { unsigned int u; float f; } v; v.u = ((unsigned int)h) << 16;
    return v.f;
}

// packed bf16x2 dot product into f32 (v_dot2_f32_bf16), with scalar fallback
#if defined(__has_builtin)
#if __has_builtin(__builtin_amdgcn_fdot2_f32_bf16)
#define HAS_DOT2BF 1
#endif
#endif
#ifdef HAS_DOT2BF
typedef __attribute__((ext_vector_type(2))) __bf16 bf16x2;
#endif
__device__ __forceinline__ float dot2bf(unsigned int a, unsigned int b, float c) {
#ifdef HAS_DOT2BF
    union { unsigned int u; bf16x2 v; } ua, ub;
    ua.u = a; ub.u = b;
    return __builtin_amdgcn_fdot2_f32_bf16(ua.v, ub.v, c, false);
#else
    return fmaf(bf2f((unsigned short)(a & 0xffffu)), bf2f((unsigned short)(b & 0xffffu)),
           fmaf(bf2f((unsigned short)(a >> 16)), bf2f((unsigned short)(b >> 16)), c));
#endif
}

// ---------------- degree counts (row for norm/deg, col for CSR) ----------------
__global__ __launch_bounds__(256) void k_deg_count(const int* __restrict__ erow,
                                                   const int* __restrict__ ecol,
                                                   int* __restrict__ degi,
                                                   int* __restrict__ indeg) {
    int e = blockIdx.x * 256 + threadIdx.x;
    if (e < NE) {
        atomicAdd(&degi[erow[e]], 1);
        atomicAdd(&indeg[ecol[e]], 1);
    }
}

__global__ __launch_bounds__(256) void k_deg_fin(const int* __restrict__ degi,
                                                 float* __restrict__ degf,
                                                 float* __restrict__ dis) {
    int n = blockIdx.x * 256 + threadIdx.x;
    if (n < NN) {
        float dg = (float)degi[n] + 1.0f;
        degf[n] = dg;
        dis[n] = rsqrtf(dg);
    }
}

// ---------------- exclusive scan of indeg -> csr_off (3-kernel) ----------------
__global__ __launch_bounds__(1024) void k_scanA(const int* __restrict__ in,
                                                int* __restrict__ part,
                                                int* __restrict__ btot) {
    const int tid = threadIdx.x;
    const int lane = tid & 63, wave = tid >> 6;
    const int i = blockIdx.x * 1024 + tid;
    int v = (i < NN) ? in[i] : 0;
    int x = v;
#pragma unroll
    for (int o = 1; o < 64; o <<= 1) {
        int t = __shfl_up(x, o);
        if (lane >= o) x += t;
    }
    __shared__ int wsum[16];
    __shared__ int blocktot;
    if (lane == 63) wsum[wave] = x;
    __syncthreads();
    if (tid < 16) {
        int t = wsum[tid];
        int y = t;
#pragma unroll
        for (int o = 1; o < 16; o <<= 1) {
            int u = __shfl_up(y, o);
            if (tid >= o) y += u;
        }
        wsum[tid] = y - t;  // exclusive wave offset
        if (tid == 15) blocktot = y;
    }
    __syncthreads();
    int excl = x - v + wsum[wave];
    if (i < NN) part[i] = excl;
    if (tid == 0) btot[blockIdx.x] = blocktot;
}

__global__ __launch_bounds__(128) void k_scanB(int* __restrict__ btot) {
    const int tid = threadIdx.x;
    const int lane = tid & 63;
    int v = (tid < NB_SCAN) ? btot[tid] : 0;
    int x = v;
#pragma unroll
    for (int o = 1; o < 64; o <<= 1) {
        int t = __shfl_up(x, o);
        if (lane >= o) x += t;
    }
    __shared__ int w2;
    if (tid == 63) w2 = x;
    __syncthreads();
    int ex = x - v + ((tid >= 64) ? w2 : 0);
    if (tid < NB_SCAN) btot[tid] = ex;
}

__global__ __launch_bounds__(256) void k_scanC(int* __restrict__ coff,
                                               const int* __restrict__ btot,
                                               int* __restrict__ cursor) {
    int i = blockIdx.x * 256 + threadIdx.x;
    if (i < NN) {
        int v = coff[i] + btot[i >> 10];
        coff[i] = v;
        cursor[i] = v;
    }
    if (i == 0) coff[NN] = NE;
}

// ---------------- CSR bucket fill (edges sorted by target) ----------------
// csrn[p] = {src, norm(fp32)}; ceab[p] = 7 bf16 attrs packed pairwise in uint4
__global__ __launch_bounds__(256) void k_csr_fill(const int* __restrict__ erow,
                                                  const int* __restrict__ ecol,
                                                  const float* __restrict__ ea,
                                                  const float* __restrict__ dis,
                                                  int* __restrict__ cursor,
                                                  int2* __restrict__ csrn,
                                                  uint4* __restrict__ ceab) {
    int e = blockIdx.x * 256 + threadIdx.x;
    if (e >= NE) return;
    const int c = ecol[e], r = erow[e];
    const int p = atomicAdd(&cursor[c], 1);
    int2 m; m.x = r; m.y = __float_as_int(dis[r] * dis[c]);
    csrn[p] = m;
    const float a0 = ea[e * 7 + 0], a1 = ea[e * 7 + 1], a2 = ea[e * 7 + 2],
                a3 = ea[e * 7 + 3], a4 = ea[e * 7 + 4], a5 = ea[e * 7 + 5],
                a6 = ea[e * 7 + 6];
    uint4 A;
    A.x = (unsigned)f2bf(a0) | ((unsigned)f2bf(a1) << 16);
    A.y = (unsigned)f2bf(a2) | ((unsigned)f2bf(a3) << 16);
    A.z = (unsigned)f2bf(a4) | ((unsigned)f2bf(a5) << 16);
    A.w = (unsigned)f2bf(a6);
    ceab[p] = A;
}

// ---------------- W pre-pack into B-fragment order, bf16 ----------------
__global__ __launch_bounds__(256) void k_wpack(const float* __restrict__ Wl,
                                               unsigned short* __restrict__ Wp) {
    int t = blockIdx.x * 256 + threadIdx.x;  // 4*5*10*64 = 12800
    if (t >= 12800) return;
    const int lane = t & 63;
    const int ct = (t >> 6) % 10;
    const int ks = ((t >> 6) / 10) % 5;
    const int l = t / (64 * 10 * 5);
    const int col = ct * 16 + (lane & 15);
    const int kbase = ks * 32 + (lane >> 4) * 8;
    unsigned short v[8];
#pragma unroll
    for (int j = 0; j < 8; ++j) {
        const int k = kbase + j;
        const float f = (k < HID && col < HID) ? Wl[(size_t)l * HID * HID + k * HID + col] : 0.f;
        v[j] = f2bf(f);
    }
    *(uint4*)(Wp + (size_t)t * 8) = *(const uint4*)v;
}

// ---------------- h init (bf16 master) ----------------
__global__ __launch_bounds__(256) void k_init_h(const int* __restrict__ x,
                                                const float* __restrict__ emb,
                                                unsigned short* __restrict__ hb) {
    int idx = blockIdx.x * 256 + threadIdx.x;
    if (idx >= NNP * LD) return;
    int n = idx / LD;
    int d = idx - n * LD;
    float v = 0.f;
    if (n < NN && d < HID) v = emb[x[n] * HID + d];
    hb[idx] = f2bf(v);
}

// ---------------- node GEMM via MFMA, with fused BN-apply + residual ----------------
// fuse=0: A = hb.   fuse=1: hn = bf2f(hb) + relu(bf2f(obuf)*sc+sh); hb <- bf16(hn); A = bf16(hn).
// Each wave owns 16 rows exclusively -> hb update race-free. Pads masked to 0.
__global__ __launch_bounds__(256) void k_gemm(unsigned short* __restrict__ hb,
                                              const unsigned short* __restrict__ obuf,
                                              const float* __restrict__ ssb,
                                              const unsigned short* __restrict__ Wp,
                                              const float* __restrict__ bias,
                                              unsigned short* __restrict__ xlb,
                                              int fuse) {
    __shared__ unsigned short Bs[5 * 10 * 64 * 8];  // 51200 B
    {
        const uint4* src = (const uint4*)Wp;
        uint4* dst = (uint4*)Bs;
        for (int i = threadIdx.x; i < 3200; i += 256) dst[i] = src[i];
    }
    __syncthreads();

    const int wave = threadIdx.x >> 6;
    const int lane = threadIdx.x & 63;
    const int row0 = (blockIdx.x * 4 + wave) * 16;
    const int rlo = lane & 15;   // A row / C col
    const int khi = lane >> 4;   // k-group
    const int row = row0 + rlo;
    const bool rowok = row < NN;

    short8 a[5];
    if (fuse) {
#pragma unroll
        for (int ks = 0; ks < 5; ++ks) {
            const int kf = ks * 32 + khi * 8;
            const size_t base = (size_t)row * LD + kf;
            const short8 hv8 = *(const short8*)(hb + base);
            const short8 ov = *(const short8*)(obuf + base);
            const float4 s0 = *(const float4*)(ssb + kf);
            const float4 s1 = *(const float4*)(ssb + kf + 4);
            const float4 t0 = *(const float4*)(ssb + LD + kf);
            const float4 t1 = *(const float4*)(ssb + LD + kf + 4);
            short8 av;
#pragma unroll
            for (int j = 0; j < 8; ++j) {
                const bool ok = rowok && (kf + j < HID);
                const float sc = (j < 4) ? (&s0.x)[j] : (&s1.x)[j - 4];
                const float sh = (j < 4) ? (&t0.x)[j] : (&t1.x)[j - 4];
                const float hf = bf2f((unsigned short)hv8[j]);
                const float o = bf2f((unsigned short)ov[j]);
                const float hn = ok ? (hf + fmaxf(o * sc + sh, 0.f)) : 0.f;
                av[j] = (short)f2bf(hn);
            }
            *(short8*)(hb + base) = av;
            a[ks] = av;
        }
    } else {
#pragma unroll
        for (int ks = 0; ks < 5; ++ks) {
            const int kf = ks * 32 + khi * 8;
            a[ks] = *(const short8*)(hb + (size_t)row * LD + kf);
        }
    }

    f32x4 acc[10];
#pragma unroll
    for (int ct = 0; ct < 10; ++ct) acc[ct] = (f32x4){0.f, 0.f, 0.f, 0.f};

    const short8* bs = (const short8*)Bs;
#pragma unroll
    for (int ks = 0; ks < 5; ++ks) {
#pragma unroll
        for (int ct = 0; ct < 10; ++ct) {
            acc[ct] = __builtin_amdgcn_mfma_f32_16x16x32_bf16(
                a[ks], bs[(ks * 10 + ct) * 64 + lane], acc[ct], 0, 0, 0);
        }
    }

    // C/D: col = ct*16 + (lane&15), row = row0 + (lane>>4)*4 + jj  [m89-verified]
#pragma unroll
    for (int ct = 0; ct < 10; ++ct) {
        const int col = ct * 16 + rlo;
        if (col < HID) {
            const float b = bias[col];
#pragma unroll
            for (int jj = 0; jj < 4; ++jj) {
                const int orow = row0 + khi * 4 + jj;
                xlb[(size_t)orow * LD + col] = f2bf(acc[ct][jj] + b);
            }
        }
    }
}

// ---------------- CSR pull-aggregation + self term + BN stats (fused) ----------------
// Feature-pair mapping: lane L owns features {2L, 2L+1}; lanes 0..10 also own
// tail {128+2L, 129+2L}. Gathers use NON-TEMPORAL loads (L1 no-allocate probe).
__global__ __launch_bounds__(256) void k_agg(const int* __restrict__ coff,
                                             const int2* __restrict__ csrn,
                                             const uint4* __restrict__ ceab,
                                             const float* __restrict__ We,
                                             const float* __restrict__ be,
                                             const float* __restrict__ root,
                                             const float* __restrict__ degf,
                                             const unsigned short* __restrict__ xlb,
                                             unsigned short* __restrict__ out,
                                             float* __restrict__ sums) {
    const int lane = threadIdx.x & 63;
    const int gw = (blockIdx.x * 256 + threadIdx.x) >> 6;
    const int nw = (gridDim.x * 256) >> 6;
    const int f0 = lane * 2;                      // features f0, f0+1 (0..127)
    const bool tl = lane < 11;
    const int ft = tl ? (128 + lane * 2) : 128;   // features ft, ft+1 (128..149)

    // per-feature We columns packed as bf16 attr-pairs: (w0,w1)(w2,w3)(w4,w5)(w6,0)
    unsigned wa[4], wb[4], wta[4], wtb[4];
    float bea, beb, bet0, bet1, rta, rtb, rtt0, rtt1;
#pragma unroll
    for (int p = 0; p < 3; ++p) {
        wa[p] = (unsigned)f2bf(We[(2 * p) * HID + f0]) | ((unsigned)f2bf(We[(2 * p + 1) * HID + f0]) << 16);
        wb[p] = (unsigned)f2bf(We[(2 * p) * HID + f0 + 1]) | ((unsigned)f2bf(We[(2 * p + 1) * HID + f0 + 1]) << 16);
        wta[p] = tl ? ((unsigned)f2bf(We[(2 * p) * HID + ft]) | ((unsigned)f2bf(We[(2 * p + 1) * HID + ft]) << 16)) : 0u;
        wtb[p] = tl ? ((unsigned)f2bf(We[(2 * p) * HID + ft + 1]) | ((unsigned)f2bf(We[(2 * p + 1) * HID + ft + 1]) << 16)) : 0u;
    }
    wa[3] = (unsigned)f2bf(We[6 * HID + f0]);
    wb[3] = (unsigned)f2bf(We[6 * HID + f0 + 1]);
    wta[3] = tl ? (unsigned)f2bf(We[6 * HID + ft]) : 0u;
    wtb[3] = tl ? (unsigned)f2bf(We[6 * HID + ft + 1]) : 0u;
    bea = be[f0]; beb = be[f0 + 1];
    bet0 = tl ? be[ft] : 0.f; bet1 = tl ? be[ft + 1] : 0.f;
    rta = root[f0]; rtb = root[f0 + 1];
    rtt0 = tl ? root[ft] : 0.f; rtt1 = tl ? root[ft + 1] : 0.f;

    float sa = 0.f, sb = 0.f, st0 = 0.f, st1 = 0.f;
    float qa = 0.f, qb = 0.f, qt0 = 0.f, qt1 = 0.f;

// NOTE: macro params AA/WW/CC/MM/XM/XT — must not collide with .x/.y/.z/.w member names
#define ENC(AA, WW, CC) dot2bf((AA).x, (WW)[0], dot2bf((AA).y, (WW)[1], dot2bf((AA).z, (WW)[2], dot2bf((AA).w, (WW)[3], (CC)))))
#define ACC_EDGE(MM, AA, XM, XT)                                                     \
    do {                                                                             \
        const float nrm = __int_as_float((MM).y);                                    \
        const float e0 = ENC(AA, wa, bea);                                           \
        const float e1 = ENC(AA, wb, beb);                                           \
        acc_a += nrm * fmaxf(bf2f((unsigned short)((XM) & 0xffffu)) + e0, 0.f);      \
        acc_b += nrm * fmaxf(bf2f((unsigned short)((XM) >> 16)) + e1, 0.f);          \
        if (tl) {                                                                    \
            const float e2 = ENC(AA, wta, bet0);                                     \
            const float e3 = ENC(AA, wtb, bet1);                                     \
            acc_t0 += nrm * fmaxf(bf2f((unsigned short)((XT) & 0xffffu)) + e2, 0.f); \
            acc_t1 += nrm * fmaxf(bf2f((unsigned short)((XT) >> 16)) + e3, 0.f);     \
        }                                                                            \
    } while (0)

    for (int i = gw; i < NN; i += nw) {
        const int j1 = coff[i + 1];
        int j = coff[i];
        float acc_a = 0.f, acc_b = 0.f, acc_t0 = 0.f, acc_t1 = 0.f;
        for (; j + 4 <= j1; j += 4) {
            const int2 m0 = csrn[j], m1 = csrn[j + 1], m2 = csrn[j + 2], m3 = csrn[j + 3];
            const uint4 A0 = ceab[j], A1 = ceab[j + 1], A2 = ceab[j + 2], A3 = ceab[j + 3];
            const unsigned short* p0 = xlb + (size_t)m0.x * LD;
            const unsigned short* p1 = xlb + (size_t)m1.x * LD;
            const unsigned short* p2 = xlb + (size_t)m2.x * LD;
            const unsigned short* p3 = xlb + (size_t)m3.x * LD;
            const unsigned x0m = __builtin_nontemporal_load((const unsigned*)(p0 + f0));
            const unsigned x1m = __builtin_nontemporal_load((const unsigned*)(p1 + f0));
            const unsigned x2m = __builtin_nontemporal_load((const unsigned*)(p2 + f0));
            const unsigned x3m = __builtin_nontemporal_load((const unsigned*)(p3 + f0));
            const unsigned x0t = tl ? __builtin_nontemporal_load((const unsigned*)(p0 + ft)) : 0u;
            const unsigned x1t = tl ? __builtin_nontemporal_load((const unsigned*)(p1 + ft)) : 0u;
            const unsigned x2t = tl ? __builtin_nontemporal_load((const unsigned*)(p2 + ft)) : 0u;
            const unsigned x3t = tl ? __builtin_nontemporal_load((const unsigned*)(p3 + ft)) : 0u;
            ACC_EDGE(m0, A0, x0m, x0t);
            ACC_EDGE(m1, A1, x1m, x1t);
            ACC_EDGE(m2, A2, x2m, x2t);
            ACC_EDGE(m3, A3, x3m, x3t);
        }
        for (; j < j1; ++j) {
            const int2 m0 = csrn[j];
            const uint4 A0 = ceab[j];
            const unsigned short* p0 = xlb + (size_t)m0.x * LD;
            const unsigned x0m = __builtin_nontemporal_load((const unsigned*)(p0 + f0));
            const unsigned x0t = tl ? __builtin_nontemporal_load((const unsigned*)(p0 + ft)) : 0u;
            ACC_EDGE(m0, A0, x0m, x0t);
        }

        const float inv = 1.0f / degf[i];
        const unsigned short* xi = xlb + (size_t)i * LD;
        unsigned short* op = out + (size_t)i * LD;
        const unsigned xim = *(const unsigned*)(xi + f0);
        const unsigned xit = tl ? *(const unsigned*)(xi + ft) : 0u;
        {
            const float oa = acc_a + fmaxf(bf2f((unsigned short)(xim & 0xffffu)) + rta, 0.f) * inv;
            const float ob = acc_b + fmaxf(bf2f((unsigned short)(xim >> 16)) + rtb, 0.f) * inv;
            *(unsigned*)(op + f0) = (unsigned)f2bf(oa) | ((unsigned)f2bf(ob) << 16);
            sa += oa; qa += oa * oa; sb += ob; qb += ob * ob;
        }
        if (tl) {
            const float ot0 = acc_t0 + fmaxf(bf2f((unsigned short)(xit & 0xffffu)) + rtt0, 0.f) * inv;
            const float ot1 = acc_t1 + fmaxf(bf2f((unsigned short)(xit >> 16)) + rtt1, 0.f) * inv;
            *(unsigned*)(op + ft) = (unsigned)f2bf(ot0) | ((unsigned)f2bf(ot1) << 16);
            st0 += ot0; qt0 += ot0 * ot0; st1 += ot1; qt1 += ot1 * ot1;
        }
    }
#undef ACC_EDGE
#undef ENC

    // block-level BN-stat reduction, then one atomic pass into a slice copy
    __shared__ float ls[2 * LD];
    for (int i = threadIdx.x; i < 2 * LD; i += 256) ls[i] = 0.f;
    __syncthreads();
    atomicAdd(&ls[f0], sa);
    atomicAdd(&ls[f0 + 1], sb);
    atomicAdd(&ls[LD + f0], qa);
    atomicAdd(&ls[LD + f0 + 1], qb);
    if (tl) {
        atomicAdd(&ls[ft], st0);
        atomicAdd(&ls[ft + 1], st1);
        atomicAdd(&ls[LD + ft], qt0);
        atomicAdd(&ls[LD + ft + 1], qt1);
    }
    __syncthreads();
    float* sl = sums + (size_t)(blockIdx.x & (NSLICE - 1)) * 2 * LD;
    for (int i = threadIdx.x; i < 2 * LD; i += 256) atomicAdd(&sl[i], ls[i]);
}

// ---------------- BN stats finalize (pads zeroed) ----------------
__global__ void k_stats(const float* __restrict__ sums, const float* __restrict__ gamma,
                        const float* __restrict__ beta, float* __restrict__ ss) {
    int d = threadIdx.x;
    if (d < HID) {
        float s = 0.f, q = 0.f;
        for (int r = 0; r < NSLICE; ++r) {
            s += sums[r * 2 * LD + d];
            q += sums[r * 2 * LD + LD + d];
        }
        const float mu = s * (1.0f / NN);
        const float var = q * (1.0f / NN) - mu * mu;
        const float inv = rsqrtf(var + BN_EPS);
        const float sc = gamma[d] * inv;
        ss[d] = sc;
        ss[LD + d] = beta[d] - mu * sc;
    } else if (d < LD) {
        ss[d] = 0.f;
        ss[LD + d] = 0.f;
    }
}

// ---------------- graph segment offsets (batch is sorted) ----------------
__global__ __launch_bounds__(256) void k_off(const int* __restrict__ batch,
                                             int* __restrict__ off) {
    int n = blockIdx.x * 256 + threadIdx.x;
    if (n >= NN) return;
    int b = batch[n];
    if (n == 0) {
        for (int g = 0; g <= b; ++g) off[g] = 0;
    } else {
        int pb = batch[n - 1];
        for (int g = pb + 1; g <= b; ++g) off[g] = n;
    }
    if (n == NN - 1) {
        for (int g = b + 1; g <= NG; ++g) off[g] = NN;
    }
}

// ---------------- pool + projection, with fused layer-3 BN-apply (no relu) ----------------
__global__ __launch_bounds__(512) void k_pool(const unsigned short* __restrict__ hb,
                                              const unsigned short* __restrict__ obuf,
                                              const float* __restrict__ ssb,
                                              const int* __restrict__ off,
                                              const float* __restrict__ Wp,
                                              const float* __restrict__ bp,
                                              float* __restrict__ out) {
    const int g = blockIdx.x;
    const int s = off[g], e = off[g + 1];
    const float cnt = fmaxf((float)(e - s), 1.0f);
    const int lane = threadIdx.x & 63;
    const int wave = threadIdx.x >> 6;
    const bool ok2 = lane < (HID - 128);
    const int d0 = lane, d1 = lane + 64;
    const int d2 = ok2 ? (lane + 128) : 0;

    const float sc0 = ssb[d0], sc1 = ssb[d1], sc2 = ok2 ? ssb[d2] : 0.f;
    const float sh0 = ssb[LD + d0], sh1 = ssb[LD + d1], sh2 = ok2 ? ssb[LD + d2] : 0.f;

    float sum0 = 0.f, sum1 = 0.f, sum2 = 0.f;
    for (int n = s + wave; n < e; n += 8) {
        const unsigned short* hp = hb + (size_t)n * LD;
        const unsigned short* op = obuf + (size_t)n * LD;
        sum0 += bf2f(hp[d0]) + (bf2f(op[d0]) * sc0 + sh0);
        sum1 += bf2f(hp[d1]) + (bf2f(op[d1]) * sc1 + sh1);
        if (ok2) sum2 += bf2f(hp[d2]) + (bf2f(op[d2]) * sc2 + sh2);
    }

    __shared__ float hg[LD];
    if (threadIdx.x < LD) hg[threadIdx.x] = 0.f;
    __syncthreads();
    atomicAdd(&hg[d0], sum0);
    atomicAdd(&hg[d1], sum1);
    if (ok2) atomicAdd(&hg[d2], sum2);
    __syncthreads();

    if (wave == 0) {
        float acc[ODIM] = {0.f, 0.f, 0.f, 0.f, 0.f, 0.f};
#pragma unroll
        for (int c = 0; c < 3; ++c) {
            const int d = c * 64 + lane;
            if (d < HID) {
                const float v = hg[d] / cnt;
#pragma unroll
                for (int o = 0; o < ODIM; ++o) acc[o] = fmaf(v, Wp[d * ODIM + o], acc[o]);
            }
        }
#pragma unroll
        for (int o = 0; o < ODIM; ++o) {
            float v = acc[o];
            for (int sh = 32; sh > 0; sh >>= 1) v += __shfl_down(v, sh);
            if (lane == 0) out[g * ODIM + o] = v + bp[o];
        }
    }
}

extern "C" void kernel_launch(void* const* d_in, const int* in_sizes, int n_in,
                              void* d_out, int out_size, void* d_ws, size_t ws_size,
                              hipStream_t stream) {
    const int* x = (const int*)d_in[0];
    const int* ei = (const int*)d_in[1];
    const float* ea = (const float*)d_in[2];
    const int* batch = (const int*)d_in[3];
    const float* emb = (const float*)d_in[4];
    const float* Wl = (const float*)d_in[5];
    const float* bl = (const float*)d_in[6];
    const float* We = (const float*)d_in[7];
    const float* be = (const float*)d_in[8];
    const float* root = (const float*)d_in[9];
    const float* gamma = (const float*)d_in[10];
    const float* beta = (const float*)d_in[11];
    const float* Wp = (const float*)d_in[12];
    const float* bp = (const float*)d_in[13];
    float* out = (float*)d_out;

    const int* erow = ei;
    const int* ecol = ei + NE;

    char* ws = (char*)d_ws;
    const size_t SZ2 = (size_t)NNP * LD * 2;  // 32,030,720
    unsigned short* hb   = (unsigned short*)(ws);
    unsigned short* xlb  = (unsigned short*)(ws + SZ2);
    unsigned short* obuf = (unsigned short*)(ws + 2 * SZ2);
    unsigned short* wpk  = (unsigned short*)(ws + 3 * SZ2);  // 204,800 B
    char* base = ws + 3 * SZ2 + 204800;
    int*   degi   = (int*)(base);
    int*   indeg  = (int*)(base + 409600);
    float* degf   = (float*)(base + 819200);
    float* dis    = (float*)(base + 1228800);
    int*   coff   = (int*)(base + 1638400);
    int*   cursor = (int*)(base + 2048000);
    int*   btot   = (int*)(base + 2457600);
    float* sums   = (float*)(base + 2461696);   // 32 slices x 320 floats
    float* ssb    = (float*)(base + 2502656);
    int*   goff   = (int*)(base + 2506752);
    int2*  csrn   = (int2*)(base + 2510848);    // NE*8 = 6,400,000 B
    uint4* ceab   = (uint4*)(base + 8910848);   // NE*16 = 12,800,000 B

    // ---- preprocess (once per launch) ----
    hipMemsetAsync(degi, 0, NN * sizeof(int), stream);
    hipMemsetAsync(indeg, 0, NN * sizeof(int), stream);
    k_deg_count<<<(NE + 255) / 256, 256, 0, stream>>>(erow, ecol, degi, indeg);
    k_deg_fin<<<(NN + 255) / 256, 256, 0, stream>>>(degi, degf, dis);
    k_scanA<<<NB_SCAN, 1024, 0, stream>>>(indeg, coff, btot);
    k_scanB<<<1, 128, 0, stream>>>(btot);
    k_scanC<<<(NN + 255) / 256, 256, 0, stream>>>(coff, btot, cursor);
    k_csr_fill<<<(NE + 255) / 256, 256, 0, stream>>>(erow, ecol, ea, dis, cursor,
                                                     csrn, ceab);
    k_wpack<<<50, 256, 0, stream>>>(Wl, wpk);
    k_init_h<<<(NNP * LD + 255) / 256, 256, 0, stream>>>(x, emb, hb);

    // ---- layers ----
    for (int l = 0; l < NL; ++l) {
        const float* b_l = bl + (size_t)l * HID;
        const float* We_l = We + (size_t)l * 7 * HID;
        const float* be_l = be + (size_t)l * HID;
        const float* root_l = root + (size_t)l * HID;
        const float* gamma_l = gamma + (size_t)l * HID;
        const float* beta_l = beta + (size_t)l * HID;
        const unsigned short* wpk_l = wpk + (size_t)l * 25600;

        // fused: for l>0, applies layer-(l-1) BN+relu+residual into hb before MFMA
        k_gemm<<<NNP / 64, 256, 0, stream>>>(hb, obuf, ssb, wpk_l, b_l, xlb,
                                             (l > 0) ? 1 : 0);
        hipMemsetAsync(sums, 0, NSLICE * 2 * LD * sizeof(float), stream);
        k_agg<<<2048, 256, 0, stream>>>(coff, csrn, ceab, We_l, be_l,
                                        root_l, degf, xlb, obuf, sums);
        k_stats<<<1, 256, 0, stream>>>(sums, gamma_l, beta_l, ssb);
    }

    // ---- pooling + projection (layer-3 BN-apply fused, no relu) ----
    k_off<<<(NN + 255) / 256, 256, 0, stream>>>(batch, goff);
    k_pool<<<NG, 512, 0, stream>>>(hb, obuf, ssb, goff, Wp, bp, out);
}

// Round 11
// 841.245 us; speedup vs baseline: 1.1841x; 1.1841x over previous
//
#include <hip/hip_runtime.h>

#define HID 150
#define LD  160
#define NN  100000
#define NNP 100096   // padded rows: 1564 blocks * 64 rows
#define NE  800000
#define NG  128
#define NL  4
#define ODIM 6
#define BN_EPS 1e-5f
#define NSLICE 32
#define NB_SCAN 98   // ceil(NN/1024)

typedef __attribute__((ext_vector_type(8))) short short8;
typedef __attribute__((ext_vector_type(4))) float f32x4;

__device__ __forceinline__ unsigned short f2bf(float f) {
    union { float f; unsigned int u; } v; v.f = f;
    unsigned int u = v.u;
    unsigned int r = (u + 0x7FFFu + ((u >> 16) & 1u)) >> 16;
    return (unsigned short)r;
}
__device__ __forceinline__ float bf2f(unsigned short h) {
    union { unsigned int u; float f; } v; v.u = ((unsigned int)h) << 16;
    return v.f;
}

// packed bf16x2 dot product into f32 (v_dot2_f32_bf16), with scalar fallback
#if defined(__has_builtin)
#if __has_builtin(__builtin_amdgcn_fdot2_f32_bf16)
#define HAS_DOT2BF 1
#endif
#endif
#ifdef HAS_DOT2BF
typedef __attribute__((ext_vector_type(2))) __bf16 bf16x2;
#endif
__device__ __forceinline__ float dot2bf(unsigned int a, unsigned int b, float c) {
#ifdef HAS_DOT2BF
    union { unsigned int u; bf16x2 v; } ua, ub;
    ua.u = a; ub.u = b;
    return __builtin_amdgcn_fdot2_f32_bf16(ua.v, ub.v, c, false);
#else
    return fmaf(bf2f((unsigned short)(a & 0xffffu)), bf2f((unsigned short)(b & 0xffffu)),
           fmaf(bf2f((unsigned short)(a >> 16)), bf2f((unsigned short)(b >> 16)), c));
#endif
}

// ---------------- degree counts (row for norm/deg, col for CSR) ----------------
__global__ __launch_bounds__(256) void k_deg_count(const int* __restrict__ erow,
                                                   const int* __restrict__ ecol,
                                                   int* __restrict__ degi,
                                                   int* __restrict__ indeg) {
    int e = blockIdx.x * 256 + threadIdx.x;
    if (e < NE) {
        atomicAdd(&degi[erow[e]], 1);
        atomicAdd(&indeg[ecol[e]], 1);
    }
}

__global__ __launch_bounds__(256) void k_deg_fin(const int* __restrict__ degi,
                                                 float* __restrict__ degf,
                                                 float* __restrict__ dis) {
    int n = blockIdx.x * 256 + threadIdx.x;
    if (n < NN) {
        float dg = (float)degi[n] + 1.0f;
        degf[n] = dg;
        dis[n] = rsqrtf(dg);
    }
}

// ---------------- exclusive scan of indeg -> csr_off (3-kernel) ----------------
__global__ __launch_bounds__(1024) void k_scanA(const int* __restrict__ in,
                                                int* __restrict__ part,
                                                int* __restrict__ btot) {
    const int tid = threadIdx.x;
    const int lane = tid & 63, wave = tid >> 6;
    const int i = blockIdx.x * 1024 + tid;
    int v = (i < NN) ? in[i] : 0;
    int x = v;
#pragma unroll
    for (int o = 1; o < 64; o <<= 1) {
        int t = __shfl_up(x, o);
        if (lane >= o) x += t;
    }
    __shared__ int wsum[16];
    __shared__ int blocktot;
    if (lane == 63) wsum[wave] = x;
    __syncthreads();
    if (tid < 16) {
        int t = wsum[tid];
        int y = t;
#pragma unroll
        for (int o = 1; o < 16; o <<= 1) {
            int u = __shfl_up(y, o);
            if (tid >= o) y += u;
        }
        wsum[tid] = y - t;  // exclusive wave offset
        if (tid == 15) blocktot = y;
    }
    __syncthreads();
    int excl = x - v + wsum[wave];
    if (i < NN) part[i] = excl;
    if (tid == 0) btot[blockIdx.x] = blocktot;
}

__global__ __launch_bounds__(128) void k_scanB(int* __restrict__ btot) {
    const int tid = threadIdx.x;
    const int lane = tid & 63;
    int v = (tid < NB_SCAN) ? btot[tid] : 0;
    int x = v;
#pragma unroll
    for (int o = 1; o < 64; o <<= 1) {
        int t = __shfl_up(x, o);
        if (lane >= o) x += t;
    }
    __shared__ int w2;
    if (tid == 63) w2 = x;
    __syncthreads();
    int ex = x - v + ((tid >= 64) ? w2 : 0);
    if (tid < NB_SCAN) btot[tid] = ex;
}

__global__ __launch_bounds__(256) void k_scanC(int* __restrict__ coff,
                                               const int* __restrict__ btot,
                                               int* __restrict__ cursor) {
    int i = blockIdx.x * 256 + threadIdx.x;
    if (i < NN) {
        int v = coff[i] + btot[i >> 10];
        coff[i] = v;
        cursor[i] = v;
    }
    if (i == 0) coff[NN] = NE;
}

// ---------------- CSR bucket fill (edges sorted by target) ----------------
// csrn[p] = {src, norm(fp32)}; ceab[p] = 7 bf16 attrs packed pairwise in uint4
__global__ __launch_bounds__(256) void k_csr_fill(const int* __restrict__ erow,
                                                  const int* __restrict__ ecol,
                                                  const float* __restrict__ ea,
                                                  const float* __restrict__ dis,
                                                  int* __restrict__ cursor,
                                                  int2* __restrict__ csrn,
                                                  uint4* __restrict__ ceab) {
    int e = blockIdx.x * 256 + threadIdx.x;
    if (e >= NE) return;
    const int c = ecol[e], r = erow[e];
    const int p = atomicAdd(&cursor[c], 1);
    int2 m; m.x = r; m.y = __float_as_int(dis[r] * dis[c]);
    csrn[p] = m;
    const float a0 = ea[e * 7 + 0], a1 = ea[e * 7 + 1], a2 = ea[e * 7 + 2],
                a3 = ea[e * 7 + 3], a4 = ea[e * 7 + 4], a5 = ea[e * 7 + 5],
                a6 = ea[e * 7 + 6];
    uint4 A;
    A.x = (unsigned)f2bf(a0) | ((unsigned)f2bf(a1) << 16);
    A.y = (unsigned)f2bf(a2) | ((unsigned)f2bf(a3) << 16);
    A.z = (unsigned)f2bf(a4) | ((unsigned)f2bf(a5) << 16);
    A.w = (unsigned)f2bf(a6);
    ceab[p] = A;
}

// ---------------- W pre-pack into B-fragment order, bf16 ----------------
__global__ __launch_bounds__(256) void k_wpack(const float* __restrict__ Wl,
                                               unsigned short* __restrict__ Wp) {
    int t = blockIdx.x * 256 + threadIdx.x;  // 4*5*10*64 = 12800
    if (t >= 12800) return;
    const int lane = t & 63;
    const int ct = (t >> 6) % 10;
    const int ks = ((t >> 6) / 10) % 5;
    const int l = t / (64 * 10 * 5);
    const int col = ct * 16 + (lane & 15);
    const int kbase = ks * 32 + (lane >> 4) * 8;
    unsigned short v[8];
#pragma unroll
    for (int j = 0; j < 8; ++j) {
        const int k = kbase + j;
        const float f = (k < HID && col < HID) ? Wl[(size_t)l * HID * HID + k * HID + col] : 0.f;
        v[j] = f2bf(f);
    }
    *(uint4*)(Wp + (size_t)t * 8) = *(const uint4*)v;
}

// ---------------- h init (bf16 master) ----------------
__global__ __launch_bounds__(256) void k_init_h(const int* __restrict__ x,
                                                const float* __restrict__ emb,
                                                unsigned short* __restrict__ hb) {
    int idx = blockIdx.x * 256 + threadIdx.x;
    if (idx >= NNP * LD) return;
    int n = idx / LD;
    int d = idx - n * LD;
    float v = 0.f;
    if (n < NN && d < HID) v = emb[x[n] * HID + d];
    hb[idx] = f2bf(v);
}

// ---------------- node GEMM via MFMA, with fused BN-apply + residual ----------------
// fuse=0: A = hb.   fuse=1: hn = bf2f(hb) + relu(bf2f(obuf)*sc+sh); hb <- bf16(hn); A = bf16(hn).
// Each wave owns 16 rows exclusively -> hb update race-free. Pads masked to 0.
__global__ __launch_bounds__(256) void k_gemm(unsigned short* __restrict__ hb,
                                              const unsigned short* __restrict__ obuf,
                                              const float* __restrict__ ssb,
                                              const unsigned short* __restrict__ Wp,
                                              const float* __restrict__ bias,
                                              unsigned short* __restrict__ xlb,
                                              int fuse) {
    __shared__ unsigned short Bs[5 * 10 * 64 * 8];  // 51200 B
    {
        const uint4* src = (const uint4*)Wp;
        uint4* dst = (uint4*)Bs;
        for (int i = threadIdx.x; i < 3200; i += 256) dst[i] = src[i];
    }
    __syncthreads();

    const int wave = threadIdx.x >> 6;
    const int lane = threadIdx.x & 63;
    const int row0 = (blockIdx.x * 4 + wave) * 16;
    const int rlo = lane & 15;   // A row / C col
    const int khi = lane >> 4;   // k-group
    const int row = row0 + rlo;
    const bool rowok = row < NN;

    short8 a[5];
    if (fuse) {
#pragma unroll
        for (int ks = 0; ks < 5; ++ks) {
            const int kf = ks * 32 + khi * 8;
            const size_t base = (size_t)row * LD + kf;
            const short8 hv8 = *(const short8*)(hb + base);
            const short8 ov = *(const short8*)(obuf + base);
            const float4 s0 = *(const float4*)(ssb + kf);
            const float4 s1 = *(const float4*)(ssb + kf + 4);
            const float4 t0 = *(const float4*)(ssb + LD + kf);
            const float4 t1 = *(const float4*)(ssb + LD + kf + 4);
            short8 av;
#pragma unroll
            for (int j = 0; j < 8; ++j) {
                const bool ok = rowok && (kf + j < HID);
                const float sc = (j < 4) ? (&s0.x)[j] : (&s1.x)[j - 4];
                const float sh = (j < 4) ? (&t0.x)[j] : (&t1.x)[j - 4];
                const float hf = bf2f((unsigned short)hv8[j]);
                const float o = bf2f((unsigned short)ov[j]);
                const float hn = ok ? (hf + fmaxf(o * sc + sh, 0.f)) : 0.f;
                av[j] = (short)f2bf(hn);
            }
            *(short8*)(hb + base) = av;
            a[ks] = av;
        }
    } else {
#pragma unroll
        for (int ks = 0; ks < 5; ++ks) {
            const int kf = ks * 32 + khi * 8;
            a[ks] = *(const short8*)(hb + (size_t)row * LD + kf);
        }
    }

    f32x4 acc[10];
#pragma unroll
    for (int ct = 0; ct < 10; ++ct) acc[ct] = (f32x4){0.f, 0.f, 0.f, 0.f};

    const short8* bs = (const short8*)Bs;
#pragma unroll
    for (int ks = 0; ks < 5; ++ks) {
#pragma unroll
        for (int ct = 0; ct < 10; ++ct) {
            acc[ct] = __builtin_amdgcn_mfma_f32_16x16x32_bf16(
                a[ks], bs[(ks * 10 + ct) * 64 + lane], acc[ct], 0, 0, 0);
        }
    }

    // C/D: col = ct*16 + (lane&15), row = row0 + (lane>>4)*4 + jj  [m89-verified]
#pragma unroll
    for (int ct = 0; ct < 10; ++ct) {
        const int col = ct * 16 + rlo;
        if (col < HID) {
            const float b = bias[col];
#pragma unroll
            for (int jj = 0; jj < 4; ++jj) {
                const int orow = row0 + khi * 4 + jj;
                xlb[(size_t)orow * LD + col] = f2bf(acc[ct][jj] + b);
            }
        }
    }
}

// ---------------- CSR pull-aggregation + self term + BN stats (fused) ----------------
// Feature-pair mapping: lane L owns features {2L, 2L+1}; lanes 0..10 also own
// tail {128+2L, 129+2L}. 2 gather loads/edge; plain loads (nt regressed: L2 hits matter).
__global__ __launch_bounds__(256) void k_agg(const int* __restrict__ coff,
                                             const int2* __restrict__ csrn,
                                             const uint4* __restrict__ ceab,
                                             const float* __restrict__ We,
                                             const float* __restrict__ be,
                                             const float* __restrict__ root,
                                             const float* __restrict__ degf,
                                             const unsigned short* __restrict__ xlb,
                                             unsigned short* __restrict__ out,
                                             float* __restrict__ sums) {
    const int lane = threadIdx.x & 63;
    const int gw = (blockIdx.x * 256 + threadIdx.x) >> 6;
    const int nw = (gridDim.x * 256) >> 6;
    const int f0 = lane * 2;                      // features f0, f0+1 (0..127)
    const bool tl = lane < 11;
    const int ft = tl ? (128 + lane * 2) : 128;   // features ft, ft+1 (128..149)

    // per-feature We columns packed as bf16 attr-pairs: (w0,w1)(w2,w3)(w4,w5)(w6,0)
    unsigned wa[4], wb[4], wta[4], wtb[4];
    float bea, beb, bet0, bet1, rta, rtb, rtt0, rtt1;
#pragma unroll
    for (int p = 0; p < 3; ++p) {
        wa[p] = (unsigned)f2bf(We[(2 * p) * HID + f0]) | ((unsigned)f2bf(We[(2 * p + 1) * HID + f0]) << 16);
        wb[p] = (unsigned)f2bf(We[(2 * p) * HID + f0 + 1]) | ((unsigned)f2bf(We[(2 * p + 1) * HID + f0 + 1]) << 16);
        wta[p] = tl ? ((unsigned)f2bf(We[(2 * p) * HID + ft]) | ((unsigned)f2bf(We[(2 * p + 1) * HID + ft]) << 16)) : 0u;
        wtb[p] = tl ? ((unsigned)f2bf(We[(2 * p) * HID + ft + 1]) | ((unsigned)f2bf(We[(2 * p + 1) * HID + ft + 1]) << 16)) : 0u;
    }
    wa[3] = (unsigned)f2bf(We[6 * HID + f0]);
    wb[3] = (unsigned)f2bf(We[6 * HID + f0 + 1]);
    wta[3] = tl ? (unsigned)f2bf(We[6 * HID + ft]) : 0u;
    wtb[3] = tl ? (unsigned)f2bf(We[6 * HID + ft + 1]) : 0u;
    bea = be[f0]; beb = be[f0 + 1];
    bet0 = tl ? be[ft] : 0.f; bet1 = tl ? be[ft + 1] : 0.f;
    rta = root[f0]; rtb = root[f0 + 1];
    rtt0 = tl ? root[ft] : 0.f; rtt1 = tl ? root[ft + 1] : 0.f;

    float sa = 0.f, sb = 0.f, st0 = 0.f, st1 = 0.f;
    float qa = 0.f, qb = 0.f, qt0 = 0.f, qt1 = 0.f;

// NOTE: macro params AA/WW/CC/MM/XM/XT — must not collide with .x/.y/.z/.w member names
#define ENC(AA, WW, CC) dot2bf((AA).x, (WW)[0], dot2bf((AA).y, (WW)[1], dot2bf((AA).z, (WW)[2], dot2bf((AA).w, (WW)[3], (CC)))))
#define ACC_EDGE(MM, AA, XM, XT)                                                     \
    do {                                                                             \
        const float nrm = __int_as_float((MM).y);                                    \
        const float e0 = ENC(AA, wa, bea);                                           \
        const float e1 = ENC(AA, wb, beb);                                           \
        acc_a += nrm * fmaxf(bf2f((unsigned short)((XM) & 0xffffu)) + e0, 0.f);      \
        acc_b += nrm * fmaxf(bf2f((unsigned short)((XM) >> 16)) + e1, 0.f);          \
        if (tl) {                                                                    \
            const float e2 = ENC(AA, wta, bet0);                                     \
            const float e3 = ENC(AA, wtb, bet1);                                     \
            acc_t0 += nrm * fmaxf(bf2f((unsigned short)((XT) & 0xffffu)) + e2, 0.f); \
            acc_t1 += nrm * fmaxf(bf2f((unsigned short)((XT) >> 16)) + e3, 0.f);     \
        }                                                                            \
    } while (0)

    for (int i = gw; i < NN; i += nw) {
        const int j1 = coff[i + 1];
        int j = coff[i];
        float acc_a = 0.f, acc_b = 0.f, acc_t0 = 0.f, acc_t1 = 0.f;
        for (; j + 4 <= j1; j += 4) {
            const int2 m0 = csrn[j], m1 = csrn[j + 1], m2 = csrn[j + 2], m3 = csrn[j + 3];
            const uint4 A0 = ceab[j], A1 = ceab[j + 1], A2 = ceab[j + 2], A3 = ceab[j + 3];
            const unsigned short* p0 = xlb + (size_t)m0.x * LD;
            const unsigned short* p1 = xlb + (size_t)m1.x * LD;
            const unsigned short* p2 = xlb + (size_t)m2.x * LD;
            const unsigned short* p3 = xlb + (size_t)m3.x * LD;
            const unsigned x0m = *(const unsigned*)(p0 + f0);
            const unsigned x1m = *(const unsigned*)(p1 + f0);
            const unsigned x2m = *(const unsigned*)(p2 + f0);
            const unsigned x3m = *(const unsigned*)(p3 + f0);
            const unsigned x0t = tl ? *(const unsigned*)(p0 + ft) : 0u;
            const unsigned x1t = tl ? *(const unsigned*)(p1 + ft) : 0u;
            const unsigned x2t = tl ? *(const unsigned*)(p2 + ft) : 0u;
            const unsigned x3t = tl ? *(const unsigned*)(p3 + ft) : 0u;
            ACC_EDGE(m0, A0, x0m, x0t);
            ACC_EDGE(m1, A1, x1m, x1t);
            ACC_EDGE(m2, A2, x2m, x2t);
            ACC_EDGE(m3, A3, x3m, x3t);
        }
        for (; j < j1; ++j) {
            const int2 m0 = csrn[j];
            const uint4 A0 = ceab[j];
            const unsigned short* p0 = xlb + (size_t)m0.x * LD;
            const unsigned x0m = *(const unsigned*)(p0 + f0);
            const unsigned x0t = tl ? *(const unsigned*)(p0 + ft) : 0u;
            ACC_EDGE(m0, A0, x0m, x0t);
        }

        const float inv = 1.0f / degf[i];
        const unsigned short* xi = xlb + (size_t)i * LD;
        unsigned short* op = out + (size_t)i * LD;
        const unsigned xim = *(const unsigned*)(xi + f0);
        const unsigned xit = tl ? *(const unsigned*)(xi + ft) : 0u;
        {
            const float oa = acc_a + fmaxf(bf2f((unsigned short)(xim & 0xffffu)) + rta, 0.f) * inv;
            const float ob = acc_b + fmaxf(bf2f((unsigned short)(xim >> 16)) + rtb, 0.f) * inv;
            *(unsigned*)(op + f0) = (unsigned)f2bf(oa) | ((unsigned)f2bf(ob) << 16);
            sa += oa; qa += oa * oa; sb += ob; qb += ob * ob;
        }
        if (tl) {
            const float ot0 = acc_t0 + fmaxf(bf2f((unsigned short)(xit & 0xffffu)) + rtt0, 0.f) * inv;
            const float ot1 = acc_t1 + fmaxf(bf2f((unsigned short)(xit >> 16)) + rtt1, 0.f) * inv;
            *(unsigned*)(op + ft) = (unsigned)f2bf(ot0) | ((unsigned)f2bf(ot1) << 16);
            st0 += ot0; qt0 += ot0 * ot0; st1 += ot1; qt1 += ot1 * ot1;
        }
    }
#undef ACC_EDGE
#undef ENC

    // block-level BN-stat reduction, then one atomic pass into a slice copy
    __shared__ float ls[2 * LD];
    for (int i = threadIdx.x; i < 2 * LD; i += 256) ls[i] = 0.f;
    __syncthreads();
    atomicAdd(&ls[f0], sa);
    atomicAdd(&ls[f0 + 1], sb);
    atomicAdd(&ls[LD + f0], qa);
    atomicAdd(&ls[LD + f0 + 1], qb);
    if (tl) {
        atomicAdd(&ls[ft], st0);
        atomicAdd(&ls[ft + 1], st1);
        atomicAdd(&ls[LD + ft], qt0);
        atomicAdd(&ls[LD + ft + 1], qt1);
    }
    __syncthreads();
    float* sl = sums + (size_t)(blockIdx.x & (NSLICE - 1)) * 2 * LD;
    for (int i = threadIdx.x; i < 2 * LD; i += 256) atomicAdd(&sl[i], ls[i]);
}

// ---------------- BN stats finalize (pads zeroed) ----------------
__global__ void k_stats(const float* __restrict__ sums, const float* __restrict__ gamma,
                        const float* __restrict__ beta, float* __restrict__ ss) {
    int d = threadIdx.x;
    if (d < HID) {
        float s = 0.f, q = 0.f;
        for (int r = 0; r < NSLICE; ++r) {
            s += sums[r * 2 * LD + d];
            q += sums[r * 2 * LD + LD + d];
        }
        const float mu = s * (1.0f / NN);
        const float var = q * (1.0f / NN) - mu * mu;
        const float inv = rsqrtf(var + BN_EPS);
        const float sc = gamma[d] * inv;
        ss[d] = sc;
        ss[LD + d] = beta[d] - mu * sc;
    } else if (d < LD) {
        ss[d] = 0.f;
        ss[LD + d] = 0.f;
    }
}

// ---------------- graph segment offsets (batch is sorted) ----------------
__global__ __launch_bounds__(256) void k_off(const int* __restrict__ batch,
                                             int* __restrict__ off) {
    int n = blockIdx.x * 256 + threadIdx.x;
    if (n >= NN) return;
    int b = batch[n];
    if (n == 0) {
        for (int g = 0; g <= b; ++g) off[g] = 0;
    } else {
        int pb = batch[n - 1];
        for (int g = pb + 1; g <= b; ++g) off[g] = n;
    }
    if (n == NN - 1) {
        for (int g = b + 1; g <= NG; ++g) off[g] = NN;
    }
}

// ---------------- pool + projection, with fused layer-3 BN-apply (no relu) ----------------
__global__ __launch_bounds__(512) void k_pool(const unsigned short* __restrict__ hb,
                                              const unsigned short* __restrict__ obuf,
                                              const float* __restrict__ ssb,
                                              const int* __restrict__ off,
                                              const float* __restrict__ Wp,
                                              const float* __restrict__ bp,
                                              float* __restrict__ out) {
    const int g = blockIdx.x;
    const int s = off[g], e = off[g + 1];
    const float cnt = fmaxf((float)(e - s), 1.0f);
    const int lane = threadIdx.x & 63;
    const int wave = threadIdx.x >> 6;
    const bool ok2 = lane < (HID - 128);
    const int d0 = lane, d1 = lane + 64;
    const int d2 = ok2 ? (lane + 128) : 0;

    const float sc0 = ssb[d0], sc1 = ssb[d1], sc2 = ok2 ? ssb[d2] : 0.f;
    const float sh0 = ssb[LD + d0], sh1 = ssb[LD + d1], sh2 = ok2 ? ssb[LD + d2] : 0.f;

    float sum0 = 0.f, sum1 = 0.f, sum2 = 0.f;
    for (int n = s + wave; n < e; n += 8) {
        const unsigned short* hp = hb + (size_t)n * LD;
        const unsigned short* op = obuf + (size_t)n * LD;
        sum0 += bf2f(hp[d0]) + (bf2f(op[d0]) * sc0 + sh0);
        sum1 += bf2f(hp[d1]) + (bf2f(op[d1]) * sc1 + sh1);
        if (ok2) sum2 += bf2f(hp[d2]) + (bf2f(op[d2]) * sc2 + sh2);
    }

    __shared__ float hg[LD];
    if (threadIdx.x < LD) hg[threadIdx.x] = 0.f;
    __syncthreads();
    atomicAdd(&hg[d0], sum0);
    atomicAdd(&hg[d1], sum1);
    if (ok2) atomicAdd(&hg[d2], sum2);
    __syncthreads();

    if (wave == 0) {
        float acc[ODIM] = {0.f, 0.f, 0.f, 0.f, 0.f, 0.f};
#pragma unroll
        for (int c = 0; c < 3; ++c) {
            const int d = c * 64 + lane;
            if (d < HID) {
                const float v = hg[d] / cnt;
#pragma unroll
                for (int o = 0; o < ODIM; ++o) acc[o] = fmaf(v, Wp[d * ODIM + o], acc[o]);
            }
        }
#pragma unroll
        for (int o = 0; o < ODIM; ++o) {
            float v = acc[o];
            for (int sh = 32; sh > 0; sh >>= 1) v += __shfl_down(v, sh);
            if (lane == 0) out[g * ODIM + o] = v + bp[o];
        }
    }
}

extern "C" void kernel_launch(void* const* d_in, const int* in_sizes, int n_in,
                              void* d_out, int out_size, void* d_ws, size_t ws_size,
                              hipStream_t stream) {
    const int* x = (const int*)d_in[0];
    const int* ei = (const int*)d_in[1];
    const float* ea = (const float*)d_in[2];
    const int* batch = (const int*)d_in[3];
    const float* emb = (const float*)d_in[4];
    const float* Wl = (const float*)d_in[5];
    const float* bl = (const float*)d_in[6];
    const float* We = (const float*)d_in[7];
    const float* be = (const float*)d_in[8];
    const float* root = (const float*)d_in[9];
    const float* gamma = (const float*)d_in[10];
    const float* beta = (const float*)d_in[11];
    const float* Wp = (const float*)d_in[12];
    const float* bp = (const float*)d_in[13];
    float* out = (float*)d_out;

    const int* erow = ei;
    const int* ecol = ei + NE;

    char* ws = (char*)d_ws;
    const size_t SZ2 = (size_t)NNP * LD * 2;  // 32,030,720
    unsigned short* hb   = (unsigned short*)(ws);
    unsigned short* xlb  = (unsigned short*)(ws + SZ2);
    unsigned short* obuf = (unsigned short*)(ws + 2 * SZ2);
    unsigned short* wpk  = (unsigned short*)(ws + 3 * SZ2);  // 204,800 B
    char* base = ws + 3 * SZ2 + 204800;
    int*   degi   = (int*)(base);
    int*   indeg  = (int*)(base + 409600);
    float* degf   = (float*)(base + 819200);
    float* dis    = (float*)(base + 1228800);
    int*   coff   = (int*)(base + 1638400);
    int*   cursor = (int*)(base + 2048000);
    int*   btot   = (int*)(base + 2457600);
    float* sums   = (float*)(base + 2461696);   // 32 slices x 320 floats
    float* ssb    = (float*)(base + 2502656);
    int*   goff   = (int*)(base + 2506752);
    int2*  csrn   = (int2*)(base + 2510848);    // NE*8 = 6,400,000 B
    uint4* ceab   = (uint4*)(base + 8910848);   // NE*16 = 12,800,000 B

    // ---- preprocess (once per launch) ----
    hipMemsetAsync(degi, 0, NN * sizeof(int), stream);
    hipMemsetAsync(indeg, 0, NN * sizeof(int), stream);
    k_deg_count<<<(NE + 255) / 256, 256, 0, stream>>>(erow, ecol, degi, indeg);
    k_deg_fin<<<(NN + 255) / 256, 256, 0, stream>>>(degi, degf, dis);
    k_scanA<<<NB_SCAN, 1024, 0, stream>>>(indeg, coff, btot);
    k_scanB<<<1, 128, 0, stream>>>(btot);
    k_scanC<<<(NN + 255) / 256, 256, 0, stream>>>(coff, btot, cursor);
    k_csr_fill<<<(NE + 255) / 256, 256, 0, stream>>>(erow, ecol, ea, dis, cursor,
                                                     csrn, ceab);
    k_wpack<<<50, 256, 0, stream>>>(Wl, wpk);
    k_init_h<<<(NNP * LD + 255) / 256, 256, 0, stream>>>(x, emb, hb);

    // ---- layers ----
    for (int l = 0; l < NL; ++l) {
        const float* b_l = bl + (size_t)l * HID;
        const float* We_l = We + (size_t)l * 7 * HID;
        const float* be_l = be + (size_t)l * HID;
        const float* root_l = root + (size_t)l * HID;
        const float* gamma_l = gamma + (size_t)l * HID;
        const float* beta_l = beta + (size_t)l * HID;
        const unsigned short* wpk_l = wpk + (size_t)l * 25600;

        // fused: for l>0, applies layer-(l-1) BN+relu+residual into hb before MFMA
        k_gemm<<<NNP / 64, 256, 0, stream>>>(hb, obuf, ssb, wpk_l, b_l, xlb,
                                             (l > 0) ? 1 : 0);
        hipMemsetAsync(sums, 0, NSLICE * 2 * LD * sizeof(float), stream);
        k_agg<<<2048, 256, 0, stream>>>(coff, csrn, ceab, We_l, be_l,
                                        root_l, degf, xlb, obuf, sums);
        k_stats<<<1, 256, 0, stream>>>(sums, gamma_l, beta_l, ssb);
    }

    // ---- pooling + projection (layer-3 BN-apply fused, no relu) ----
    k_off<<<(NN + 255) / 256, 256, 0, stream>>>(batch, goff);
    k_pool<<<NG, 512, 0, stream>>>(hb, obuf, ssb, goff, Wp, bp, out);
}

// Round 14
// 829.217 us; speedup vs baseline: 1.2012x; 1.0145x over previous
//
#include <hip/hip_runtime.h>

#define HID 150
#define LD  160
#define NN  100000
#define NNP 100096   // padded rows: 1564 blocks * 64 rows
#define NE  800000
#define NG  128
#define NL  4
#define ODIM 6
#define BN_EPS 1e-5f
#define NSLICE 32
#define NB_SCAN 98   // ceil(NN/1024)

typedef __attribute__((ext_vector_type(8))) short short8;
typedef __attribute__((ext_vector_type(4))) float f32x4;

__device__ __forceinline__ unsigned short f2bf(float f) {
    union { float f; unsigned int u; } v; v.f = f;
    unsigned int u = v.u;
    unsigned int r = (u + 0x7FFFu + ((u >> 16) & 1u)) >> 16;
    return (unsigned short)r;
}
__device__ __forceinline__ float bf2f(unsigned short h) {
    union { unsigned int u; float f; } v; v.u = ((unsigned int)h) << 16;
    return v.f;
}

// packed bf16x2 dot product into f32 (v_dot2_f32_bf16), with scalar fallback
#if defined(__has_builtin)
#if __has_builtin(__builtin_amdgcn_fdot2_f32_bf16)
#define HAS_DOT2BF 1
#endif
#endif
#ifdef HAS_DOT2BF
typedef __attribute__((ext_vector_type(2))) __bf16 bf16x2;
#endif
__device__ __forceinline__ float dot2bf(unsigned int a, unsigned int b, float c) {
#ifdef HAS_DOT2BF
    union { unsigned int u; bf16x2 v; } ua, ub;
    ua.u = a; ub.u = b;
    return __builtin_amdgcn_fdot2_f32_bf16(ua.v, ub.v, c, false);
#else
    return fmaf(bf2f((unsigned short)(a & 0xffffu)), bf2f((unsigned short)(b & 0xffffu)),
           fmaf(bf2f((unsigned short)(a >> 16)), bf2f((unsigned short)(b >> 16)), c));
#endif
}

// ---------------- degree counts (row for norm/deg, col for CSR) ----------------
__global__ __launch_bounds__(256) void k_deg_count(const int* __restrict__ erow,
                                                   const int* __restrict__ ecol,
                                                   int* __restrict__ degi,
                                                   int* __restrict__ indeg) {
    int e = blockIdx.x * 256 + threadIdx.x;
    if (e < NE) {
        atomicAdd(&degi[erow[e]], 1);
        atomicAdd(&indeg[ecol[e]], 1);
    }
}

__global__ __launch_bounds__(256) void k_deg_fin(const int* __restrict__ degi,
                                                 float* __restrict__ degf,
                                                 float* __restrict__ dis) {
    int n = blockIdx.x * 256 + threadIdx.x;
    if (n < NN) {
        float dg = (float)degi[n] + 1.0f;
        degf[n] = dg;
        dis[n] = rsqrtf(dg);
    }
}

// ---------------- exclusive scan of indeg -> csr_off (3-kernel) ----------------
__global__ __launch_bounds__(1024) void k_scanA(const int* __restrict__ in,
                                                int* __restrict__ part,
                                                int* __restrict__ btot) {
    const int tid = threadIdx.x;
    const int lane = tid & 63, wave = tid >> 6;
    const int i = blockIdx.x * 1024 + tid;
    int v = (i < NN) ? in[i] : 0;
    int x = v;
#pragma unroll
    for (int o = 1; o < 64; o <<= 1) {
        int t = __shfl_up(x, o);
        if (lane >= o) x += t;
    }
    __shared__ int wsum[16];
    __shared__ int blocktot;
    if (lane == 63) wsum[wave] = x;
    __syncthreads();
    if (tid < 16) {
        int t = wsum[tid];
        int y = t;
#pragma unroll
        for (int o = 1; o < 16; o <<= 1) {
            int u = __shfl_up(y, o);
            if (tid >= o) y += u;
        }
        wsum[tid] = y - t;  // exclusive wave offset
        if (tid == 15) blocktot = y;
    }
    __syncthreads();
    int excl = x - v + wsum[wave];
    if (i < NN) part[i] = excl;
    if (tid == 0) btot[blockIdx.x] = blocktot;
}

__global__ __launch_bounds__(128) void k_scanB(int* __restrict__ btot) {
    const int tid = threadIdx.x;
    const int lane = tid & 63;
    int v = (tid < NB_SCAN) ? btot[tid] : 0;
    int x = v;
#pragma unroll
    for (int o = 1; o < 64; o <<= 1) {
        int t = __shfl_up(x, o);
        if (lane >= o) x += t;
    }
    __shared__ int w2;
    if (tid == 63) w2 = x;
    __syncthreads();
    int ex = x - v + ((tid >= 64) ? w2 : 0);
    if (tid < NB_SCAN) btot[tid] = ex;
}

__global__ __launch_bounds__(256) void k_scanC(int* __restrict__ coff,
                                               const int* __restrict__ btot,
                                               int* __restrict__ cursor) {
    int i = blockIdx.x * 256 + threadIdx.x;
    if (i < NN) {
        int v = coff[i] + btot[i >> 10];
        coff[i] = v;
        cursor[i] = v;
    }
    if (i == 0) coff[NN] = NE;
}

// ---------------- CSR bucket fill (edges sorted by target) ----------------
// csrn[p] = {src, norm(fp32)}; ceab[p] = 7 bf16 attrs packed pairwise in uint4
__global__ __launch_bounds__(256) void k_csr_fill(const int* __restrict__ erow,
                                                  const int* __restrict__ ecol,
                                                  const float* __restrict__ ea,
                                                  const float* __restrict__ dis,
                                                  int* __restrict__ cursor,
                                                  int2* __restrict__ csrn,
                                                  uint4* __restrict__ ceab) {
    int e = blockIdx.x * 256 + threadIdx.x;
    if (e >= NE) return;
    const int c = ecol[e], r = erow[e];
    const int p = atomicAdd(&cursor[c], 1);
    int2 m; m.x = r; m.y = __float_as_int(dis[r] * dis[c]);
    csrn[p] = m;
    const float a0 = ea[e * 7 + 0], a1 = ea[e * 7 + 1], a2 = ea[e * 7 + 2],
                a3 = ea[e * 7 + 3], a4 = ea[e * 7 + 4], a5 = ea[e * 7 + 5],
                a6 = ea[e * 7 + 6];
    uint4 A;
    A.x = (unsigned)f2bf(a0) | ((unsigned)f2bf(a1) << 16);
    A.y = (unsigned)f2bf(a2) | ((unsigned)f2bf(a3) << 16);
    A.z = (unsigned)f2bf(a4) | ((unsigned)f2bf(a5) << 16);
    A.w = (unsigned)f2bf(a6);
    ceab[p] = A;
}

// ---------------- W pre-pack into B-fragment order, bf16 ----------------
__global__ __launch_bounds__(256) void k_wpack(const float* __restrict__ Wl,
                                               unsigned short* __restrict__ Wp) {
    int t = blockIdx.x * 256 + threadIdx.x;  // 4*5*10*64 = 12800
    if (t >= 12800) return;
    const int lane = t & 63;
    const int ct = (t >> 6) % 10;
    const int ks = ((t >> 6) / 10) % 5;
    const int l = t / (64 * 10 * 5);
    const int col = ct * 16 + (lane & 15);
    const int kbase = ks * 32 + (lane >> 4) * 8;
    unsigned short v[8];
#pragma unroll
    for (int j = 0; j < 8; ++j) {
        const int k = kbase + j;
        const float f = (k < HID && col < HID) ? Wl[(size_t)l * HID * HID + k * HID + col] : 0.f;
        v[j] = f2bf(f);
    }
    *(uint4*)(Wp + (size_t)t * 8) = *(const uint4*)v;
}

// ---------------- h init (bf16 master) ----------------
__global__ __launch_bounds__(256) void k_init_h(const int* __restrict__ x,
                                                const float* __restrict__ emb,
                                                unsigned short* __restrict__ hb) {
    int idx = blockIdx.x * 256 + threadIdx.x;
    if (idx >= NNP * LD) return;
    int n = idx / LD;
    int d = idx - n * LD;
    float v = 0.f;
    if (n < NN && d < HID) v = emb[x[n] * HID + d];
    hb[idx] = f2bf(v);
}

// ---------------- node GEMM via MFMA, with fused BN-apply + residual ----------------
// fuse=0: A = hb.   fuse=1: hn = bf2f(hb) + relu(bf2f(obuf)*sc+sh); hb <- bf16(hn); A = bf16(hn).
// Each wave owns 16 rows exclusively -> hb update race-free. Pads masked to 0.
__global__ __launch_bounds__(256) void k_gemm(unsigned short* __restrict__ hb,
                                              const unsigned short* __restrict__ obuf,
                                              const float* __restrict__ ssb,
                                              const unsigned short* __restrict__ Wp,
                                              const float* __restrict__ bias,
                                              unsigned short* __restrict__ xlb,
                                              int fuse) {
    __shared__ unsigned short Bs[5 * 10 * 64 * 8];  // 51200 B
    {
        const uint4* src = (const uint4*)Wp;
        uint4* dst = (uint4*)Bs;
        for (int i = threadIdx.x; i < 3200; i += 256) dst[i] = src[i];
    }
    __syncthreads();

    const int wave = threadIdx.x >> 6;
    const int lane = threadIdx.x & 63;
    const int row0 = (blockIdx.x * 4 + wave) * 16;
    const int rlo = lane & 15;   // A row / C col
    const int khi = lane >> 4;   // k-group
    const int row = row0 + rlo;
    const bool rowok = row < NN;

    short8 a[5];
    if (fuse) {
#pragma unroll
        for (int ks = 0; ks < 5; ++ks) {
            const int kf = ks * 32 + khi * 8;
            const size_t base = (size_t)row * LD + kf;
            const short8 hv8 = *(const short8*)(hb + base);
            const short8 ov = *(const short8*)(obuf + base);
            const float4 s0 = *(const float4*)(ssb + kf);
            const float4 s1 = *(const float4*)(ssb + kf + 4);
            const float4 t0 = *(const float4*)(ssb + LD + kf);
            const float4 t1 = *(const float4*)(ssb + LD + kf + 4);
            short8 av;
#pragma unroll
            for (int j = 0; j < 8; ++j) {
                const bool ok = rowok && (kf + j < HID);
                const float sc = (j < 4) ? (&s0.x)[j] : (&s1.x)[j - 4];
                const float sh = (j < 4) ? (&t0.x)[j] : (&t1.x)[j - 4];
                const float hf = bf2f((unsigned short)hv8[j]);
                const float o = bf2f((unsigned short)ov[j]);
                const float hn = ok ? (hf + fmaxf(o * sc + sh, 0.f)) : 0.f;
                av[j] = (short)f2bf(hn);
            }
            *(short8*)(hb + base) = av;
            a[ks] = av;
        }
    } else {
#pragma unroll
        for (int ks = 0; ks < 5; ++ks) {
            const int kf = ks * 32 + khi * 8;
            a[ks] = *(const short8*)(hb + (size_t)row * LD + kf);
        }
    }

    f32x4 acc[10];
#pragma unroll
    for (int ct = 0; ct < 10; ++ct) acc[ct] = (f32x4){0.f, 0.f, 0.f, 0.f};

    const short8* bs = (const short8*)Bs;
#pragma unroll
    for (int ks = 0; ks < 5; ++ks) {
#pragma unroll
        for (int ct = 0; ct < 10; ++ct) {
            acc[ct] = __builtin_amdgcn_mfma_f32_16x16x32_bf16(
                a[ks], bs[(ks * 10 + ct) * 64 + lane], acc[ct], 0, 0, 0);
        }
    }

    // C/D: col = ct*16 + (lane&15), row = row0 + (lane>>4)*4 + jj  [m89-verified]
#pragma unroll
    for (int ct = 0; ct < 10; ++ct) {
        const int col = ct * 16 + rlo;
        if (col < HID) {
            const float b = bias[col];
#pragma unroll
            for (int jj = 0; jj < 4; ++jj) {
                const int orow = row0 + khi * 4 + jj;
                xlb[(size_t)orow * LD + col] = f2bf(acc[ct][jj] + b);
            }
        }
    }
}

// ---------------- CSR pull-aggregation + self term + BN stats (fused) ----------------
// Feature-pair mapping: lane L owns features {2L, 2L+1}; lanes 0..10 also own
// tail {128+2L, 129+2L}. 2 gather loads/edge; plain loads (nt regressed: L2 hits matter).
__global__ __launch_bounds__(256) void k_agg(const int* __restrict__ coff,
                                             const int2* __restrict__ csrn,
                                             const uint4* __restrict__ ceab,
                                             const float* __restrict__ We,
                                             const float* __restrict__ be,
                                             const float* __restrict__ root,
                                             const float* __restrict__ degf,
                                             const unsigned short* __restrict__ xlb,
                                             unsigned short* __restrict__ out,
                                             float* __restrict__ sums) {
    const int lane = threadIdx.x & 63;
    const int gw = (blockIdx.x * 256 + threadIdx.x) >> 6;
    const int nw = (gridDim.x * 256) >> 6;
    const int f0 = lane * 2;                      // features f0, f0+1 (0..127)
    const bool tl = lane < 11;
    const int ft = tl ? (128 + lane * 2) : 128;   // features ft, ft+1 (128..149)

    // per-feature We columns packed as bf16 attr-pairs: (w0,w1)(w2,w3)(w4,w5)(w6,0)
    unsigned wa[4], wb[4], wta[4], wtb[4];
    float bea, beb, bet0, bet1, rta, rtb, rtt0, rtt1;
#pragma unroll
    for (int p = 0; p < 3; ++p) {
        wa[p] = (unsigned)f2bf(We[(2 * p) * HID + f0]) | ((unsigned)f2bf(We[(2 * p + 1) * HID + f0]) << 16);
        wb[p] = (unsigned)f2bf(We[(2 * p) * HID + f0 + 1]) | ((unsigned)f2bf(We[(2 * p + 1) * HID + f0 + 1]) << 16);
        wta[p] = tl ? ((unsigned)f2bf(We[(2 * p) * HID + ft]) | ((unsigned)f2bf(We[(2 * p + 1) * HID + ft]) << 16)) : 0u;
        wtb[p] = tl ? ((unsigned)f2bf(We[(2 * p) * HID + ft + 1]) | ((unsigned)f2bf(We[(2 * p + 1) * HID + ft + 1]) << 16)) : 0u;
    }
    wa[3] = (unsigned)f2bf(We[6 * HID + f0]);
    wb[3] = (unsigned)f2bf(We[6 * HID + f0 + 1]);
    wta[3] = tl ? (unsigned)f2bf(We[6 * HID + ft]) : 0u;
    wtb[3] = tl ? (unsigned)f2bf(We[6 * HID + ft + 1]) : 0u;
    bea = be[f0]; beb = be[f0 + 1];
    bet0 = tl ? be[ft] : 0.f; bet1 = tl ? be[ft + 1] : 0.f;
    rta = root[f0]; rtb = root[f0 + 1];
    rtt0 = tl ? root[ft] : 0.f; rtt1 = tl ? root[ft + 1] : 0.f;

    float sa = 0.f, sb = 0.f, st0 = 0.f, st1 = 0.f;
    float qa = 0.f, qb = 0.f, qt0 = 0.f, qt1 = 0.f;

// NOTE: macro params AA/WW/CC/MM/XM/XT — must not collide with .x/.y/.z/.w member names
#define ENC(AA, WW, CC) dot2bf((AA).x, (WW)[0], dot2bf((AA).y, (WW)[1], dot2bf((AA).z, (WW)[2], dot2bf((AA).w, (WW)[3], (CC)))))
#define ACC_EDGE(MM, AA, XM, XT)                                                     \
    do {                                                                             \
        const float nrm = __int_as_float((MM).y);                                    \
        const float e0 = ENC(AA, wa, bea);                                           \
        const float e1 = ENC(AA, wb, beb);                                           \
        acc_a += nrm * fmaxf(bf2f((unsigned short)((XM) & 0xffffu)) + e0, 0.f);      \
        acc_b += nrm * fmaxf(bf2f((unsigned short)((XM) >> 16)) + e1, 0.f);          \
        if (tl) {                                                                    \
            const float e2 = ENC(AA, wta, bet0);                                     \
            const float e3 = ENC(AA, wtb, bet1);                                     \
            acc_t0 += nrm * fmaxf(bf2f((unsigned short)((XT) & 0xffffu)) + e2, 0.f); \
            acc_t1 += nrm * fmaxf(bf2f((unsigned short)((XT) >> 16)) + e3, 0.f);     \
        }                                                                            \
    } while (0)

    for (int i = gw; i < NN; i += nw) {
        const int j1 = coff[i + 1];
        int j = coff[i];
        float acc_a = 0.f, acc_b = 0.f, acc_t0 = 0.f, acc_t1 = 0.f;
        for (; j + 4 <= j1; j += 4) {
            const int2 m0 = csrn[j], m1 = csrn[j + 1], m2 = csrn[j + 2], m3 = csrn[j + 3];
            const uint4 A0 = ceab[j], A1 = ceab[j + 1], A2 = ceab[j + 2], A3 = ceab[j + 3];
            const unsigned short* p0 = xlb + (size_t)m0.x * LD;
            const unsigned short* p1 = xlb + (size_t)m1.x * LD;
            const unsigned short* p2 = xlb + (size_t)m2.x * LD;
            const unsigned short* p3 = xlb + (size_t)m3.x * LD;
            const unsigned x0m = *(const unsigned*)(p0 + f0);
            const unsigned x1m = *(const unsigned*)(p1 + f0);
            const unsigned x2m = *(const unsigned*)(p2 + f0);
            const unsigned x3m = *(const unsigned*)(p3 + f0);
            const unsigned x0t = tl ? *(const unsigned*)(p0 + ft) : 0u;
            const unsigned x1t = tl ? *(const unsigned*)(p1 + ft) : 0u;
            const unsigned x2t = tl ? *(const unsigned*)(p2 + ft) : 0u;
            const unsigned x3t = tl ? *(const unsigned*)(p3 + ft) : 0u;
            ACC_EDGE(m0, A0, x0m, x0t);
            ACC_EDGE(m1, A1, x1m, x1t);
            ACC_EDGE(m2, A2, x2m, x2t);
            ACC_EDGE(m3, A3, x3m, x3t);
        }
        for (; j < j1; ++j) {
            const int2 m0 = csrn[j];
            const uint4 A0 = ceab[j];
            const unsigned short* p0 = xlb + (size_t)m0.x * LD;
            const unsigned x0m = *(const unsigned*)(p0 + f0);
            const unsigned x0t = tl ? *(const unsigned*)(p0 + ft) : 0u;
            ACC_EDGE(m0, A0, x0m, x0t);
        }

        const float inv = 1.0f / degf[i];
        const unsigned short* xi = xlb + (size_t)i * LD;
        unsigned short* op = out + (size_t)i * LD;
        const unsigned xim = *(const unsigned*)(xi + f0);
        const unsigned xit = tl ? *(const unsigned*)(xi + ft) : 0u;
        {
            const float oa = acc_a + fmaxf(bf2f((unsigned short)(xim & 0xffffu)) + rta, 0.f) * inv;
            const float ob = acc_b + fmaxf(bf2f((unsigned short)(xim >> 16)) + rtb, 0.f) * inv;
            *(unsigned*)(op + f0) = (unsigned)f2bf(oa) | ((unsigned)f2bf(ob) << 16);
            sa += oa; qa += oa * oa; sb += ob; qb += ob * ob;
        }
        if (tl) {
            const float ot0 = acc_t0 + fmaxf(bf2f((unsigned short)(xit & 0xffffu)) + rtt0, 0.f) * inv;
            const float ot1 = acc_t1 + fmaxf(bf2f((unsigned short)(xit >> 16)) + rtt1, 0.f) * inv;
            *(unsigned*)(op + ft) = (unsigned)f2bf(ot0) | ((unsigned)f2bf(ot1) << 16);
            st0 += ot0; qt0 += ot0 * ot0; st1 += ot1; qt1 += ot1 * ot1;
        }
    }
#undef ACC_EDGE
#undef ENC

    // block-level BN-stat reduction, then one atomic pass into a slice copy
    __shared__ float ls[2 * LD];
    for (int i = threadIdx.x; i < 2 * LD; i += 256) ls[i] = 0.f;
    __syncthreads();
    atomicAdd(&ls[f0], sa);
    atomicAdd(&ls[f0 + 1], sb);
    atomicAdd(&ls[LD + f0], qa);
    atomicAdd(&ls[LD + f0 + 1], qb);
    if (tl) {
        atomicAdd(&ls[ft], st0);
        atomicAdd(&ls[ft + 1], st1);
        atomicAdd(&ls[LD + ft], qt0);
        atomicAdd(&ls[LD + ft + 1], qt1);
    }
    __syncthreads();
    float* sl = sums + (size_t)(blockIdx.x & (NSLICE - 1)) * 2 * LD;
    for (int i = threadIdx.x; i < 2 * LD; i += 256) atomicAdd(&sl[i], ls[i]);
}

// ---------------- BN stats finalize (pads zeroed) ----------------
__global__ void k_stats(const float* __restrict__ sums, const float* __restrict__ gamma,
                        const float* __restrict__ beta, float* __restrict__ ss) {
    int d = threadIdx.x;
    if (d < HID) {
        float s = 0.f, q = 0.f;
        for (int r = 0; r < NSLICE; ++r) {
            s += sums[r * 2 * LD + d];
            q += sums[r * 2 * LD + LD + d];
        }
        const float mu = s * (1.0f / NN);
        const float var = q * (1.0f / NN) - mu * mu;
        const float inv = rsqrtf(var + BN_EPS);
        const float sc = gamma[d] * inv;
        ss[d] = sc;
        ss[LD + d] = beta[d] - mu * sc;
    } else if (d < LD) {
        ss[d] = 0.f;
        ss[LD + d] = 0.f;
    }
}

// ---------------- graph segment offsets (batch is sorted) ----------------
__global__ __launch_bounds__(256) void k_off(const int* __restrict__ batch,
                                             int* __restrict__ off) {
    int n = blockIdx.x * 256 + threadIdx.x;
    if (n >= NN) return;
    int b = batch[n];
    if (n == 0) {
        for (int g = 0; g <= b; ++g) off[g] = 0;
    } else {
        int pb = batch[n - 1];
        for (int g = pb + 1; g <= b; ++g) off[g] = n;
    }
    if (n == NN - 1) {
        for (int g = b + 1; g <= NG; ++g) off[g] = NN;
    }
}

// ---------------- pool + projection, with fused layer-3 BN-apply (no relu) ----------------
__global__ __launch_bounds__(512) void k_pool(const unsigned short* __restrict__ hb,
                                              const unsigned short* __restrict__ obuf,
                                              const float* __restrict__ ssb,
                                              const int* __restrict__ off,
                                              const float* __restrict__ Wp,
                                              const float* __restrict__ bp,
                                              float* __restrict__ out) {
    const int g = blockIdx.x;
    const int s = off[g], e = off[g + 1];
    const float cnt = fmaxf((float)(e - s), 1.0f);
    const int lane = threadIdx.x & 63;
    const int wave = threadIdx.x >> 6;
    const bool ok2 = lane < (HID - 128);
    const int d0 = lane, d1 = lane + 64;
    const int d2 = ok2 ? (lane + 128) : 0;

    const float sc0 = ssb[d0], sc1 = ssb[d1], sc2 = ok2 ? ssb[d2] : 0.f;
    const float sh0 = ssb[LD + d0], sh1 = ssb[LD + d1], sh2 = ok2 ? ssb[LD + d2] : 0.f;

    float sum0 = 0.f, sum1 = 0.f, sum2 = 0.f;
    for (int n = s + wave; n < e; n += 8) {
        const unsigned short* hp = hb + (size_t)n * LD;
        const unsigned short* op = obuf + (size_t)n * LD;
        sum0 += bf2f(hp[d0]) + (bf2f(op[d0]) * sc0 + sh0);
        sum1 += bf2f(hp[d1]) + (bf2f(op[d1]) * sc1 + sh1);
        if (ok2) sum2 += bf2f(hp[d2]) + (bf2f(op[d2]) * sc2 + sh2);
    }

    __shared__ float hg[LD];
    if (threadIdx.x < LD) hg[threadIdx.x] = 0.f;
    __syncthreads();
    atomicAdd(&hg[d0], sum0);
    atomicAdd(&hg[d1], sum1);
    if (ok2) atomicAdd(&hg[d2], sum2);
    __syncthreads();

    if (wave == 0) {
        float acc[ODIM] = {0.f, 0.f, 0.f, 0.f, 0.f, 0.f};
#pragma unroll
        for (int c = 0; c < 3; ++c) {
            const int d = c * 64 + lane;
            if (d < HID) {
                const float v = hg[d] / cnt;
#pragma unroll
                for (int o = 0; o < ODIM; ++o) acc[o] = fmaf(v, Wp[d * ODIM + o], acc[o]);
            }
        }
#pragma unroll
        for (int o = 0; o < ODIM; ++o) {
            float v = acc[o];
            for (int sh = 32; sh > 0; sh >>= 1) v += __shfl_down(v, sh);
            if (lane == 0) out[g * ODIM + o] = v + bp[o];
        }
    }
}

extern "C" void kernel_launch(void* const* d_in, const int* in_sizes, int n_in,
                              void* d_out, int out_size, void* d_ws, size_t ws_size,
                              hipStream_t stream) {
    const int* x = (const int*)d_in[0];
    const int* ei = (const int*)d_in[1];
    const float* ea = (const float*)d_in[2];
    const int* batch = (const int*)d_in[3];
    const float* emb = (const float*)d_in[4];
    const float* Wl = (const float*)d_in[5];
    const float* bl = (const float*)d_in[6];
    const float* We = (const float*)d_in[7];
    const float* be = (const float*)d_in[8];
    const float* root = (const float*)d_in[9];
    const float* gamma = (const float*)d_in[10];
    const float* beta = (const float*)d_in[11];
    const float* Wp = (const float*)d_in[12];
    const float* bp = (const float*)d_in[13];
    float* out = (float*)d_out;

    const int* erow = ei;
    const int* ecol = ei + NE;

    char* ws = (char*)d_ws;
    const size_t SZ2 = (size_t)NNP * LD * 2;  // 32,030,720
    unsigned short* hb   = (unsigned short*)(ws);
    unsigned short* xlb  = (unsigned short*)(ws + SZ2);
    unsigned short* obuf = (unsigned short*)(ws + 2 * SZ2);
    unsigned short* wpk  = (unsigned short*)(ws + 3 * SZ2);  // 204,800 B
    char* base = ws + 3 * SZ2 + 204800;
    int*   degi   = (int*)(base);
    int*   indeg  = (int*)(base + 409600);
    float* degf   = (float*)(base + 819200);
    float* dis    = (float*)(base + 1228800);
    int*   coff   = (int*)(base + 1638400);
    int*   cursor = (int*)(base + 2048000);
    int*   btot   = (int*)(base + 2457600);
    float* sums   = (float*)(base + 2461696);   // 32 slices x 320 floats
    float* ssb    = (float*)(base + 2502656);
    int*   goff   = (int*)(base + 2506752);
    int2*  csrn   = (int2*)(base + 2510848);    // NE*8 = 6,400,000 B
    uint4* ceab   = (uint4*)(base + 8910848);   // NE*16 = 12,800,000 B

    // ---- preprocess (once per launch) ----
    hipMemsetAsync(degi, 0, NN * sizeof(int), stream);
    hipMemsetAsync(indeg, 0, NN * sizeof(int), stream);
    k_deg_count<<<(NE + 255) / 256, 256, 0, stream>>>(erow, ecol, degi, indeg);
    k_deg_fin<<<(NN + 255) / 256, 256, 0, stream>>>(degi, degf, dis);
    k_scanA<<<NB_SCAN, 1024, 0, stream>>>(indeg, coff, btot);
    k_scanB<<<1, 128, 0, stream>>>(btot);
    k_scanC<<<(NN + 255) / 256, 256, 0, stream>>>(coff, btot, cursor);
    k_csr_fill<<<(NE + 255) / 256, 256, 0, stream>>>(erow, ecol, ea, dis, cursor,
                                                     csrn, ceab);
    k_wpack<<<50, 256, 0, stream>>>(Wl, wpk);
    k_init_h<<<(NNP * LD + 255) / 256, 256, 0, stream>>>(x, emb, hb);

    // ---- layers ----
    for (int l = 0; l < NL; ++l) {
        const float* b_l = bl + (size_t)l * HID;
        const float* We_l = We + (size_t)l * 7 * HID;
        const float* be_l = be + (size_t)l * HID;
        const float* root_l = root + (size_t)l * HID;
        const float* gamma_l = gamma + (size_t)l * HID;
        const float* beta_l = beta + (size_t)l * HID;
        const unsigned short* wpk_l = wpk + (size_t)l * 25600;

        // fused: for l>0, applies layer-(l-1) BN+relu+residual into hb before MFMA
        k_gemm<<<NNP / 64, 256, 0, stream>>>(hb, obuf, ssb, wpk_l, b_l, xlb,
                                             (l > 0) ? 1 : 0);
        hipMemsetAsync(sums, 0, NSLICE * 2 * LD * sizeof(float), stream);
        k_agg<<<2048, 256, 0, stream>>>(coff, csrn, ceab, We_l, be_l,
                                        root_l, degf, xlb, obuf, sums);
        k_stats<<<1, 256, 0, stream>>>(sums, gamma_l, beta_l, ssb);
    }

    // ---- pooling + projection (layer-3 BN-apply fused, no relu) ----
    k_off<<<(NN + 255) / 256, 256, 0, stream>>>(batch, goff);
    k_pool<<<NG, 512, 0, stream>>>(hb, obuf, ssb, goff, Wp, bp, out);
}